// Round 1
// baseline (278.395 us; speedup 1.0000x reference)
//
#include <hip/hip_runtime.h>

// VQ-VAE VectorQuantizer: fp16 single-term MFMA distance + exact fp32 fallback.
// z: (32,64,64,64) NCHW fp32; codebook: (1024,64) fp32.
// d_out: [0]=loss, [1..]=z_q (NCHW).
//
// R9 (from R8): R8 was latency/serialization-bound (MfmaUtil 20%, VALUBusy 31%,
// both pipes idle ~45% of chunk time). Two levers:
//  1) single-term fp16 MFMA replaces the 3-term bf16 hi/lo split: 12->4 MFMAs
//     per t8, acc chains 6->2, staging bytes halve, cbl plane gone. Precision
//     moves to vq_fix: fp16 distance error sigma~1e-3 (realistic max ~7e-3),
//     TAU raised 2.5e-4 -> 0.05 flags ~1-2K queries for exact fp32 re-rank.
//  2) double-buffered LDS chunks, ONE barrier per chunk: stage(c+1) issued
//     BEFORE compute(c); the barrier's implicit vmcnt(0) drain lands after
//     ~2800cyc of compute, hiding L2 stage latency (was: stage->drain->compute
//     phase-locked across the 4 co-resident blocks).

#define CB_N   1024
#define KDIM   64
#define HWD    4096
#define CHW    (KDIM * HWD)
#define NQ     131072
#define TOTALF 8388608.0f
#define TAU    0.05f
#define FCAP   16384
#define CHUNK  128            // codes per LDS chunk
#define NCHUNK (CB_N / CHUNK)

typedef __attribute__((ext_vector_type(8))) _Float16 half8;
typedef __attribute__((ext_vector_type(4))) float    f32x4;

// async 16B/lane global->LDS copy (wave-uniform contiguous; m97 pattern)
__device__ __forceinline__ void gload_lds16(const void* g, void* l) {
    __builtin_amdgcn_global_load_lds(
        (const __attribute__((address_space(1))) unsigned int*)g,
        (__attribute__((address_space(3))) unsigned int*)l,
        16, 0, 0);
}

// ---------- ws layout (byte offsets) ----------
// 0: loss_acc  4: flag_cnt  8: done_cnt
// 128:    norms   f32[1024]
// 4224:   cbh_sw  u16[1024*64]   (fp16, XOR-rotate-swizzled row segments)
// 266368: flag_q i32[FCAP]  331904: flag_m1 f32[FCAP]  397440: flag_idx i32[FCAP]

// ---------------- prep: fp16 convert, swizzled rows, norms, counters --------
__global__ void vq_prep(const float* __restrict__ cb,
                        float* __restrict__ norms,
                        unsigned short* __restrict__ cbh,
                        float* __restrict__ loss_acc,
                        int* __restrict__ flag_cnt,
                        int* __restrict__ done_cnt) {
    const int tid = blockIdx.x * 256 + threadIdx.x;
    if (tid == 0) *loss_acc = 0.0f;
    if (tid == 1) *flag_cnt = 0;
    if (tid == 2) *done_cnt = 0;
    const int j  = tid >> 2;
    const int s2 = tid & 3;

    const float4* r4 = (const float4*)(cb + (size_t)j * KDIM);
    float s_norm = 0.0f;
    #pragma unroll
    for (int seg8 = 0; seg8 < 2; ++seg8) {
        const int s = s2 * 2 + seg8;
        float4 v0 = r4[s * 2 + 0];
        float4 v1 = r4[s * 2 + 1];
        float e[8] = {v0.x, v0.y, v0.z, v0.w, v1.x, v1.y, v1.z, v1.w};
        unsigned hh[4];
        #pragma unroll
        for (int c = 0; c < 8; ++c) {
            float x = e[c];
            s_norm = fmaf(x, x, s_norm);
            union { _Float16 h; unsigned short u; } cv;
            cv.h = (_Float16)x;                       // RNE fp16
            if ((c & 1) == 0) hh[c >> 1] = cv.u;
            else              hh[c >> 1] |= ((unsigned)cv.u) << 16;
        }
        const int p = (s + j) & 7;                    // bank-deconflict rotate
        *(uint4*)(cbh + (size_t)j * KDIM + p * 8) = make_uint4(hh[0], hh[1], hh[2], hh[3]);
    }
    s_norm += __shfl_xor(s_norm, 1, 64);
    s_norm += __shfl_xor(s_norm, 2, 64);
    if (s2 == 0) norms[j] = s_norm;
}

// ---------------- main ------------------------------------------------------
__global__ __launch_bounds__(256, 4) void vq_main(
        const float* __restrict__ z,
        const float* __restrict__ cb,
        const unsigned short* __restrict__ cbh,
        const float* __restrict__ norms,
        float* __restrict__ out,
        float* __restrict__ loss_acc,
        int* __restrict__ flag_q,
        float* __restrict__ flag_m1,
        int* __restrict__ flag_idx,
        int* __restrict__ flag_cnt) {
    __shared__ float          norms_s[CB_N];             // 4 KB
    __shared__ unsigned short bh_s[2][CHUNK * KDIM];     // 2 x 16 KB (dbuf)
    __shared__ float          zn_s[128];
    __shared__ int            idx_s[128];

    const int tid  = threadIdx.x;
    const int w    = tid >> 6;
    const int lane = tid & 63;
    const int quad = lane >> 4;
    const int l16  = lane & 15;
    const int qb   = blockIdx.x * 128;     // block's 128 queries (same batch b)
    const int b    = qb >> 12;
    const int hw0  = qb & 4095;
    const int ch0  = blockIdx.x & (NCHUNK - 1);   // de-phase chunk start

    // ---- issue stage of chunk 0 FIRST (flies under the z-read prologue)
    {
        const char* gh = (const char*)cbh + (size_t)((0 + ch0) & (NCHUNK - 1)) * (CHUNK * KDIM * 2);
        char* lh = (char*)(&bh_s[0][0]);
        #pragma unroll
        for (int i = 0; i < 4; ++i) {
            const int off = (w * 4 + i) * 1024 + lane * 16;
            gload_lds16(gh + off, lh + off);
        }
    }

    // ---- stage all code norms into LDS
    *(float4*)(norms_s + tid * 4) = *(const float4*)(norms + tid * 4);

    // ---- stage A-frags: wave w owns queries [32w, 32w+32); 2 tiles of 16.
    const float* zbase = z + (size_t)b * CHW + hw0 + 32 * w;
    half8 ah[2][2];
    float znp[2] = {0.f, 0.f};
    #pragma unroll
    for (int t = 0; t < 2; ++t)
        #pragma unroll
        for (int ks = 0; ks < 2; ++ks)
            #pragma unroll
            for (int j = 0; j < 8; ++j) {
                float v = zbase[(size_t)(ks * 32 + quad * 8 + j) * HWD + t * 16 + l16];
                znp[t] = fmaf(v, v, znp[t]);
                ah[t][ks][j] = (_Float16)(-2.0f * v);   // RNE fp16
            }
    #pragma unroll
    for (int t = 0; t < 2; ++t) {
        znp[t] += __shfl_xor(znp[t], 16, 64);
        znp[t] += __shfl_xor(znp[t], 32, 64);
    }
    if (lane < 16) {
        zn_s[32 * w + lane]      = znp[0];
        zn_s[32 * w + 16 + lane] = znp[1];
    }

    float m1[2][4], m2[2][4];
    int   i1[2][4];
    #pragma unroll
    for (int t = 0; t < 2; ++t)
        #pragma unroll
        for (int r = 0; r < 4; ++r) { m1[t][r] = 3.4e38f; m2[t][r] = 3.4e38f; i1[t][r] = 0; }

    // loop-invariant swizzled segment offsets (ks=0 / ks=1)
    const int p0 = ((quad + l16) & 7) * 8;
    const int p1 = ((4 + quad + l16) & 7) * 8;

    f32x4 bank[2][2];               // [tile-parity][t] -- deferred tracking
    bank[0][0] = bank[0][1] = (f32x4){0.f, 0.f, 0.f, 0.f};
    bank[1][0] = bank[1][1] = (f32x4){0.f, 0.f, 0.f, 0.f};
    int prevCode = 0;

    __syncthreads();                // chunk 0 staged + norms_s/zn_s visible
    int cur = 0;

    for (int cc = 0; cc < NCHUNK; ++cc) {
        // ---- issue next chunk's stage into the OTHER buffer (overlaps compute)
        if (cc + 1 < NCHUNK) {
            const int chn = (cc + 1 + ch0) & (NCHUNK - 1);
            const char* gh = (const char*)cbh + (size_t)chn * (CHUNK * KDIM * 2);
            char* lh = (char*)(&bh_s[cur ^ 1][0]);
            #pragma unroll
            for (int i = 0; i < 4; ++i) {
                const int off = (w * 4 + i) * 1024 + lane * 16;
                gload_lds16(gh + off, lh + off);
            }
        }

        const int ch = (cc + ch0) & (NCHUNK - 1);
        #pragma unroll
        for (int t8 = 0; t8 < 8; ++t8) {
            const int crow = t8 * 16 + l16;            // chunk-local code row
            const float nv = norms_s[ch * CHUNK + crow];
            const half8 bh0 = *(const half8*)(&bh_s[cur][crow * KDIM + p0]);
            const half8 bh1 = *(const half8*)(&bh_s[cur][crow * KDIM + p1]);
            const int code = ch * CHUNK + crow;
            const int bk = t8 & 1, pv = bk ^ 1;

            // track the DEFERRED tile (previous t8) held in bank[pv];
            // independent of bank[bk]'s MFMAs below -> overlaps them
            if (cc + t8 > 0) {
                #pragma unroll
                for (int t = 0; t < 2; ++t)
                    #pragma unroll
                    for (int r = 0; r < 4; ++r) {
                        float d = bank[pv][t][r];
                        bool cnd = d < m1[t][r];
                        m2[t][r] = __builtin_amdgcn_fmed3f(d, m1[t][r], m2[t][r]);
                        m1[t][r] = fminf(m1[t][r], d);
                        i1[t][r] = cnd ? prevCode : i1[t][r];
                    }
            }

            #pragma unroll
            for (int t = 0; t < 2; ++t) {
                f32x4 acc = {nv, nv, nv, nv};
                acc = __builtin_amdgcn_mfma_f32_16x16x32_f16(ah[t][0], bh0, acc, 0, 0, 0);
                acc = __builtin_amdgcn_mfma_f32_16x16x32_f16(ah[t][1], bh1, acc, 0, 0, 0);
                bank[bk][t] = acc;
            }
            prevCode = code;
        }

        __syncthreads();   // implicit vmcnt(0): next buffer landed; cur reads done
        cur ^= 1;
    }
    // final deferred tile (last t8=7 wrote bank[1])
    {
        #pragma unroll
        for (int t = 0; t < 2; ++t)
            #pragma unroll
            for (int r = 0; r < 4; ++r) {
                float d = bank[1][t][r];
                bool cnd = d < m1[t][r];
                m2[t][r] = __builtin_amdgcn_fmed3f(d, m1[t][r], m2[t][r]);
                m1[t][r] = fminf(m1[t][r], d);
                i1[t][r] = cnd ? prevCode : i1[t][r];
            }
    }

    // ---- merge across 16 lanes (code residues), first-index ties
    #pragma unroll
    for (int s = 1; s < 16; s <<= 1)
        #pragma unroll
        for (int t = 0; t < 2; ++t)
            #pragma unroll
            for (int r = 0; r < 4; ++r) {
                float o1 = __shfl_xor(m1[t][r], s, 64);
                int   oi = __shfl_xor(i1[t][r], s, 64);
                float o2 = __shfl_xor(m2[t][r], s, 64);
                m2[t][r] = __builtin_amdgcn_fmed3f(m1[t][r], o1, fminf(m2[t][r], o2));
                if (o1 < m1[t][r] || (o1 == m1[t][r] && oi < i1[t][r])) {
                    m1[t][r] = o1; i1[t][r] = oi;
                }
            }

    // ---- owners (l16==0): publish idx, flags, loss partial
    float lsum = 0.0f;
    if (l16 == 0) {
        #pragma unroll
        for (int t = 0; t < 2; ++t)
            #pragma unroll
            for (int r = 0; r < 4; ++r) {
                const int ql = 32 * w + t * 16 + quad * 4 + r;
                idx_s[ql] = i1[t][r];
                lsum += m1[t][r] + zn_s[ql];
                if (m2[t][r] - m1[t][r] < TAU) {
                    int pos = atomicAdd(flag_cnt, 1);
                    if (pos < FCAP) {
                        flag_q[pos]   = qb + ql;
                        flag_m1[pos]  = m1[t][r];
                        flag_idx[pos] = i1[t][r];
                    }
                }
            }
    }
    #pragma unroll
    for (int s = 1; s < 64; s <<= 1) lsum += __shfl_xor(lsum, s, 64);
    if (lane == 0) atomicAdd(loss_acc, lsum);
    __syncthreads();

    // ---- epilogue: thread -> (query tid&127, channels [32*(tid>>7),+32))
    {
        const int q   = tid & 127;
        const int cs  = (tid >> 7) * 32;
        const int idx = idx_s[q];
        const float4* row = (const float4*)(cb + (size_t)idx * KDIM + cs);
        float* op = out + 1 + (size_t)b * CHW + (size_t)cs * HWD + hw0 + q;
        #pragma unroll
        for (int i4 = 0; i4 < 8; ++i4) {
            float4 v = row[i4];
            op[(size_t)(i4 * 4 + 0) * HWD] = v.x;
            op[(size_t)(i4 * 4 + 1) * HWD] = v.y;
            op[(size_t)(i4 * 4 + 2) * HWD] = v.z;
            op[(size_t)(i4 * 4 + 3) * HWD] = v.w;
        }
    }
}

// ---------------- fix: exact fp32 re-rank for flagged queries + finalize ----
__global__ void vq_fix(const float* __restrict__ z,
                       const float* __restrict__ cb,
                       float* __restrict__ out,
                       float* __restrict__ loss_acc,
                       const int* __restrict__ flag_q,
                       const float* __restrict__ flag_m1,
                       const int* __restrict__ flag_idx,
                       const int* __restrict__ flag_cnt,
                       int* __restrict__ done_cnt) {
    const int w    = threadIdx.x >> 6;
    const int lane = threadIdx.x & 63;
    const int gw   = blockIdx.x * 4 + w;
    const int NW   = gridDim.x * 4;

    int n = *flag_cnt;
    if (n > FCAP) n = FCAP;

    for (int f = gw; f < n; f += NW) {
        const int   q   = flag_q[f];
        const float m1o = flag_m1[f];
        const int   io  = flag_idx[f];
        const int   b   = q >> 12;
        const int   hw  = q & 4095;

        float zv[KDIM];
        float znorm = 0.0f;
        #pragma unroll
        for (int k = 0; k < KDIM; ++k) {
            zv[k] = z[(size_t)b * CHW + (size_t)k * HWD + hw];
            znorm = fmaf(zv[k], zv[k], znorm);
        }
        float best = 3.4e38f; int bj = 0;
        for (int i = 0; i < 16; ++i) {
            const int j = lane * 16 + i;
            const float4* row = (const float4*)(cb + (size_t)j * KDIM);
            float d = 0.0f;
            #pragma unroll
            for (int k4 = 0; k4 < 16; ++k4) {
                float4 v = row[k4];
                float t0 = zv[k4 * 4 + 0] - v.x;
                float t1 = zv[k4 * 4 + 1] - v.y;
                float t2 = zv[k4 * 4 + 2] - v.z;
                float t3 = zv[k4 * 4 + 3] - v.w;
                d = fmaf(t0, t0, d); d = fmaf(t1, t1, d);
                d = fmaf(t2, t2, d); d = fmaf(t3, t3, d);
            }
            if (d < best) { best = d; bj = j; }
        }
        #pragma unroll
        for (int s = 1; s < 64; s <<= 1) {
            float ob = __shfl_xor(best, s, 64);
            int   oj = __shfl_xor(bj, s, 64);
            if (ob < best || (ob == best && oj < bj)) { best = ob; bj = oj; }
        }
        if (bj != io) {
            out[1 + (size_t)b * CHW + (size_t)lane * HWD + hw] = cb[(size_t)bj * KDIM + lane];
            if (lane == 0) atomicAdd(loss_acc, best - (m1o + znorm));
        }
    }

    __syncthreads();
    if (threadIdx.x == 0) {
        __threadfence();
        int old = atomicAdd(done_cnt, 1);
        if (old == (int)gridDim.x - 1) {
            float L = atomicAdd(loss_acc, 0.0f);
            out[0] = 1.25f * L / TOTALF;
        }
    }
}

extern "C" void kernel_launch(void* const* d_in, const int* in_sizes, int n_in,
                              void* d_out, int out_size, void* d_ws, size_t ws_size,
                              hipStream_t stream) {
    const float* z  = (const float*)d_in[0];
    const float* cb = (const float*)d_in[1];
    float* out      = (float*)d_out;
    char*  ws       = (char*)d_ws;

    float*          loss_acc = (float*)(ws + 0);
    int*            flag_cnt = (int*)(ws + 4);
    int*            done_cnt = (int*)(ws + 8);
    float*          norms    = (float*)(ws + 128);
    unsigned short* cbh      = (unsigned short*)(ws + 4224);
    int*            flag_q   = (int*)(ws + 266368);
    float*          flag_m1  = (float*)(ws + 331904);
    int*            flag_idx = (int*)(ws + 397440);

    vq_prep<<<dim3(16), dim3(256), 0, stream>>>(cb, norms, cbh,
                                                loss_acc, flag_cnt, done_cnt);

    vq_main<<<dim3(NQ / 128), dim3(256), 0, stream>>>(z, cb, cbh, norms, out,
                                                      loss_acc, flag_q, flag_m1,
                                                      flag_idx, flag_cnt);

    vq_fix<<<dim3(256), dim3(256), 0, stream>>>(z, cb, out, loss_acc,
                                                flag_q, flag_m1, flag_idx,
                                                flag_cnt, done_cnt);
}

// Round 2
// 195.663 us; speedup vs baseline: 1.4228x; 1.4228x over previous
//
#include <hip/hip_runtime.h>

// VQ-VAE VectorQuantizer: fp16 single-term MFMA distance + exact fp32 fallback.
// z: (32,64,64,64) NCHW fp32; codebook: (1024,64) fp32.
// d_out: [0]=loss, [1..]=z_q (NCHW).
//
// R10 (from R9 post-mortem):
//  - R9's launch_bounds(256,4) squeezed VGPR to 64 -> ~3 dwords/thread/chunk
//    scratch spill (WRITE_SIZE 35->61 MB). Back to (256,3) (R8's 76-VGPR cfg).
//  - Killed the loss atomic convoy: 4096 same-address atomicAdd+barrier-drain
//    serialized the whole resident grid. Now: per-block partial -> plain store
//    to loss_part[1024]; vq_fix's last block parallel-reduces them.
//  - Flag atomics batched: count locally, ONE atomicAdd(nf) per owner thread
//    (skipped when 0), then indexed writes. TAU 0.05 -> 0.02 (>=8 sigma of
//    fp16 comparison error) to shrink vq_fix's exact re-rank population.
//  - Keeps: fp16 single-term MFMA (4 MFMA/t8), double-buffered LDS chunks
//    with one barrier per chunk, deferred min-tracking banks.

#define CB_N   1024
#define KDIM   64
#define HWD    4096
#define CHW    (KDIM * HWD)
#define NQ     131072
#define TOTALF 8388608.0f
#define TAU    0.02f
#define FCAP   16384
#define CHUNK  128            // codes per LDS chunk
#define NCHUNK (CB_N / CHUNK)

typedef __attribute__((ext_vector_type(8))) _Float16 half8;
typedef __attribute__((ext_vector_type(4))) float    f32x4;

// async 16B/lane global->LDS copy (wave-uniform contiguous; m97 pattern)
__device__ __forceinline__ void gload_lds16(const void* g, void* l) {
    __builtin_amdgcn_global_load_lds(
        (const __attribute__((address_space(1))) unsigned int*)g,
        (__attribute__((address_space(3))) unsigned int*)l,
        16, 0, 0);
}

// ---------- ws layout (byte offsets) ----------
// 0: loss_adj  4: flag_cnt  8: done_cnt
// 128:    loss_part f32[1024]
// 4224:   norms     f32[1024]
// 8320:   cbh_sw    u16[1024*64]   (fp16, rotate-swizzled row segments)
// 266368: flag_q i32[FCAP]  331904: flag_m1 f32[FCAP]  397440: flag_idx i32[FCAP]

// ---------------- prep: fp16 convert, swizzled rows, norms, counters --------
__global__ void vq_prep(const float* __restrict__ cb,
                        float* __restrict__ norms,
                        unsigned short* __restrict__ cbh,
                        float* __restrict__ loss_adj,
                        int* __restrict__ flag_cnt,
                        int* __restrict__ done_cnt) {
    const int tid = blockIdx.x * 256 + threadIdx.x;
    if (tid == 0) *loss_adj = 0.0f;
    if (tid == 1) *flag_cnt = 0;
    if (tid == 2) *done_cnt = 0;
    const int j  = tid >> 2;
    const int s2 = tid & 3;

    const float4* r4 = (const float4*)(cb + (size_t)j * KDIM);
    float s_norm = 0.0f;
    #pragma unroll
    for (int seg8 = 0; seg8 < 2; ++seg8) {
        const int s = s2 * 2 + seg8;
        float4 v0 = r4[s * 2 + 0];
        float4 v1 = r4[s * 2 + 1];
        float e[8] = {v0.x, v0.y, v0.z, v0.w, v1.x, v1.y, v1.z, v1.w};
        unsigned hh[4];
        #pragma unroll
        for (int c = 0; c < 8; ++c) {
            float x = e[c];
            s_norm = fmaf(x, x, s_norm);
            union { _Float16 h; unsigned short u; } cv;
            cv.h = (_Float16)x;                       // RNE fp16
            if ((c & 1) == 0) hh[c >> 1] = cv.u;
            else              hh[c >> 1] |= ((unsigned)cv.u) << 16;
        }
        const int p = (s + j) & 7;                    // bank-deconflict rotate
        *(uint4*)(cbh + (size_t)j * KDIM + p * 8) = make_uint4(hh[0], hh[1], hh[2], hh[3]);
    }
    s_norm += __shfl_xor(s_norm, 1, 64);
    s_norm += __shfl_xor(s_norm, 2, 64);
    if (s2 == 0) norms[j] = s_norm;
}

// ---------------- main ------------------------------------------------------
__global__ __launch_bounds__(256, 3) void vq_main(
        const float* __restrict__ z,
        const float* __restrict__ cb,
        const unsigned short* __restrict__ cbh,
        const float* __restrict__ norms,
        float* __restrict__ out,
        float* __restrict__ loss_part,
        int* __restrict__ flag_q,
        float* __restrict__ flag_m1,
        int* __restrict__ flag_idx,
        int* __restrict__ flag_cnt) {
    __shared__ float          norms_s[CB_N];             // 4 KB
    __shared__ unsigned short bh_s[2][CHUNK * KDIM];     // 2 x 16 KB (dbuf)
    __shared__ float          zn_s[128];
    __shared__ int            idx_s[128];
    __shared__ float          wsum_s[4];

    const int tid  = threadIdx.x;
    const int w    = tid >> 6;
    const int lane = tid & 63;
    const int quad = lane >> 4;
    const int l16  = lane & 15;
    const int qb   = blockIdx.x * 128;     // block's 128 queries (same batch b)
    const int b    = qb >> 12;
    const int hw0  = qb & 4095;
    const int ch0  = blockIdx.x & (NCHUNK - 1);   // de-phase chunk start

    // ---- issue stage of chunk 0 FIRST (flies under the z-read prologue)
    {
        const char* gh = (const char*)cbh + (size_t)(ch0 & (NCHUNK - 1)) * (CHUNK * KDIM * 2);
        char* lh = (char*)(&bh_s[0][0]);
        #pragma unroll
        for (int i = 0; i < 4; ++i) {
            const int off = (w * 4 + i) * 1024 + lane * 16;
            gload_lds16(gh + off, lh + off);
        }
    }

    // ---- stage all code norms into LDS
    *(float4*)(norms_s + tid * 4) = *(const float4*)(norms + tid * 4);

    // ---- stage A-frags: wave w owns queries [32w, 32w+32); 2 tiles of 16.
    const float* zbase = z + (size_t)b * CHW + hw0 + 32 * w;
    half8 ah[2][2];
    float znp[2] = {0.f, 0.f};
    #pragma unroll
    for (int t = 0; t < 2; ++t)
        #pragma unroll
        for (int ks = 0; ks < 2; ++ks)
            #pragma unroll
            for (int j = 0; j < 8; ++j) {
                float v = zbase[(size_t)(ks * 32 + quad * 8 + j) * HWD + t * 16 + l16];
                znp[t] = fmaf(v, v, znp[t]);
                ah[t][ks][j] = (_Float16)(-2.0f * v);   // RNE fp16
            }
    #pragma unroll
    for (int t = 0; t < 2; ++t) {
        znp[t] += __shfl_xor(znp[t], 16, 64);
        znp[t] += __shfl_xor(znp[t], 32, 64);
    }
    if (lane < 16) {
        zn_s[32 * w + lane]      = znp[0];
        zn_s[32 * w + 16 + lane] = znp[1];
    }

    float m1[2][4], m2[2][4];
    int   i1[2][4];
    #pragma unroll
    for (int t = 0; t < 2; ++t)
        #pragma unroll
        for (int r = 0; r < 4; ++r) { m1[t][r] = 3.4e38f; m2[t][r] = 3.4e38f; i1[t][r] = 0; }

    // loop-invariant swizzled segment offsets (ks=0 / ks=1)
    const int p0 = ((quad + l16) & 7) * 8;
    const int p1 = ((4 + quad + l16) & 7) * 8;

    f32x4 bank[2][2];               // [tile-parity][t] -- deferred tracking
    bank[0][0] = bank[0][1] = (f32x4){0.f, 0.f, 0.f, 0.f};
    bank[1][0] = bank[1][1] = (f32x4){0.f, 0.f, 0.f, 0.f};
    int prevCode = 0;

    __syncthreads();                // chunk 0 staged + norms_s/zn_s visible
    int cur = 0;

    for (int cc = 0; cc < NCHUNK; ++cc) {
        // ---- issue next chunk's stage into the OTHER buffer (overlaps compute)
        if (cc + 1 < NCHUNK) {
            const int chn = (cc + 1 + ch0) & (NCHUNK - 1);
            const char* gh = (const char*)cbh + (size_t)chn * (CHUNK * KDIM * 2);
            char* lh = (char*)(&bh_s[cur ^ 1][0]);
            #pragma unroll
            for (int i = 0; i < 4; ++i) {
                const int off = (w * 4 + i) * 1024 + lane * 16;
                gload_lds16(gh + off, lh + off);
            }
        }

        const int ch = (cc + ch0) & (NCHUNK - 1);
        #pragma unroll
        for (int t8 = 0; t8 < 8; ++t8) {
            const int crow = t8 * 16 + l16;            // chunk-local code row
            const float nv = norms_s[ch * CHUNK + crow];
            const half8 bh0 = *(const half8*)(&bh_s[cur][crow * KDIM + p0]);
            const half8 bh1 = *(const half8*)(&bh_s[cur][crow * KDIM + p1]);
            const int code = ch * CHUNK + crow;
            const int bk = t8 & 1, pv = bk ^ 1;

            // track the DEFERRED tile (previous t8) held in bank[pv];
            // independent of bank[bk]'s MFMAs below -> overlaps them
            if (cc + t8 > 0) {
                #pragma unroll
                for (int t = 0; t < 2; ++t)
                    #pragma unroll
                    for (int r = 0; r < 4; ++r) {
                        float d = bank[pv][t][r];
                        bool cnd = d < m1[t][r];
                        m2[t][r] = __builtin_amdgcn_fmed3f(d, m1[t][r], m2[t][r]);
                        m1[t][r] = fminf(m1[t][r], d);
                        i1[t][r] = cnd ? prevCode : i1[t][r];
                    }
            }

            #pragma unroll
            for (int t = 0; t < 2; ++t) {
                f32x4 acc = {nv, nv, nv, nv};
                acc = __builtin_amdgcn_mfma_f32_16x16x32_f16(ah[t][0], bh0, acc, 0, 0, 0);
                acc = __builtin_amdgcn_mfma_f32_16x16x32_f16(ah[t][1], bh1, acc, 0, 0, 0);
                bank[bk][t] = acc;
            }
            prevCode = code;
        }

        __syncthreads();   // implicit vmcnt(0): next buffer landed; cur reads done
        cur ^= 1;
    }
    // final deferred tile (last t8=7 wrote bank[1])
    {
        #pragma unroll
        for (int t = 0; t < 2; ++t)
            #pragma unroll
            for (int r = 0; r < 4; ++r) {
                float d = bank[1][t][r];
                bool cnd = d < m1[t][r];
                m2[t][r] = __builtin_amdgcn_fmed3f(d, m1[t][r], m2[t][r]);
                m1[t][r] = fminf(m1[t][r], d);
                i1[t][r] = cnd ? prevCode : i1[t][r];
            }
    }

    // ---- merge across 16 lanes (code residues), first-index ties
    #pragma unroll
    for (int s = 1; s < 16; s <<= 1)
        #pragma unroll
        for (int t = 0; t < 2; ++t)
            #pragma unroll
            for (int r = 0; r < 4; ++r) {
                float o1 = __shfl_xor(m1[t][r], s, 64);
                int   oi = __shfl_xor(i1[t][r], s, 64);
                float o2 = __shfl_xor(m2[t][r], s, 64);
                m2[t][r] = __builtin_amdgcn_fmed3f(m1[t][r], o1, fminf(m2[t][r], o2));
                if (o1 < m1[t][r] || (o1 == m1[t][r] && oi < i1[t][r])) {
                    m1[t][r] = o1; i1[t][r] = oi;
                }
            }

    // ---- owners (l16==0): publish idx, batched flags, loss partial
    float lsum = 0.0f;
    if (l16 == 0) {
        int nf = 0;
        #pragma unroll
        for (int t = 0; t < 2; ++t)
            #pragma unroll
            for (int r = 0; r < 4; ++r) {
                const int ql = 32 * w + t * 16 + quad * 4 + r;
                idx_s[ql] = i1[t][r];
                lsum += m1[t][r] + zn_s[ql];
                nf += (m2[t][r] - m1[t][r] < TAU) ? 1 : 0;
            }
        if (nf) {                      // ONE atomic per flagging owner thread
            int pos = atomicAdd(flag_cnt, nf);
            #pragma unroll
            for (int t = 0; t < 2; ++t)
                #pragma unroll
                for (int r = 0; r < 4; ++r)
                    if (m2[t][r] - m1[t][r] < TAU) {
                        if (pos < FCAP) {
                            flag_q[pos]   = qb + 32 * w + t * 16 + quad * 4 + r;
                            flag_m1[pos]  = m1[t][r];
                            flag_idx[pos] = i1[t][r];
                        }
                        ++pos;
                    }
        }
    }
    #pragma unroll
    for (int s = 1; s < 64; s <<= 1) lsum += __shfl_xor(lsum, s, 64);
    if (lane == 0) wsum_s[w] = lsum;
    __syncthreads();                   // idx_s + wsum_s visible

    // per-block loss partial: plain store, NO global atomic
    if (tid == 0)
        loss_part[blockIdx.x] = wsum_s[0] + wsum_s[1] + wsum_s[2] + wsum_s[3];

    // ---- epilogue: thread -> (query tid&127, channels [32*(tid>>7),+32))
    {
        const int q   = tid & 127;
        const int cs  = (tid >> 7) * 32;
        const int idx = idx_s[q];
        const float4* row = (const float4*)(cb + (size_t)idx * KDIM + cs);
        float* op = out + 1 + (size_t)b * CHW + (size_t)cs * HWD + hw0 + q;
        #pragma unroll
        for (int i4 = 0; i4 < 8; ++i4) {
            float4 v = row[i4];
            op[(size_t)(i4 * 4 + 0) * HWD] = v.x;
            op[(size_t)(i4 * 4 + 1) * HWD] = v.y;
            op[(size_t)(i4 * 4 + 2) * HWD] = v.z;
            op[(size_t)(i4 * 4 + 3) * HWD] = v.w;
        }
    }
}

// ---------------- fix: exact fp32 re-rank for flagged queries + finalize ----
__global__ void vq_fix(const float* __restrict__ z,
                       const float* __restrict__ cb,
                       float* __restrict__ out,
                       float* __restrict__ loss_adj,
                       const float* __restrict__ loss_part,
                       const int* __restrict__ flag_q,
                       const float* __restrict__ flag_m1,
                       const int* __restrict__ flag_idx,
                       const int* __restrict__ flag_cnt,
                       int* __restrict__ done_cnt) {
    __shared__ float red_s[4];
    __shared__ int   last_s;

    const int w    = threadIdx.x >> 6;
    const int lane = threadIdx.x & 63;
    const int gw   = blockIdx.x * 4 + w;
    const int NW   = gridDim.x * 4;

    int n = *flag_cnt;
    if (n > FCAP) n = FCAP;

    for (int f = gw; f < n; f += NW) {
        const int   q   = flag_q[f];
        const float m1o = flag_m1[f];
        const int   io  = flag_idx[f];
        const int   b   = q >> 12;
        const int   hw  = q & 4095;

        float zv[KDIM];
        float znorm = 0.0f;
        #pragma unroll
        for (int k = 0; k < KDIM; ++k) {
            zv[k] = z[(size_t)b * CHW + (size_t)k * HWD + hw];
            znorm = fmaf(zv[k], zv[k], znorm);
        }
        float best = 3.4e38f; int bj = 0;
        for (int i = 0; i < 16; ++i) {
            const int j = lane * 16 + i;
            const float4* row = (const float4*)(cb + (size_t)j * KDIM);
            float d = 0.0f;
            #pragma unroll
            for (int k4 = 0; k4 < 16; ++k4) {
                float4 v = row[k4];
                float t0 = zv[k4 * 4 + 0] - v.x;
                float t1 = zv[k4 * 4 + 1] - v.y;
                float t2 = zv[k4 * 4 + 2] - v.z;
                float t3 = zv[k4 * 4 + 3] - v.w;
                d = fmaf(t0, t0, d); d = fmaf(t1, t1, d);
                d = fmaf(t2, t2, d); d = fmaf(t3, t3, d);
            }
            if (d < best) { best = d; bj = j; }
        }
        #pragma unroll
        for (int s = 1; s < 64; s <<= 1) {
            float ob = __shfl_xor(best, s, 64);
            int   oj = __shfl_xor(bj, s, 64);
            if (ob < best || (ob == best && oj < bj)) { best = ob; bj = oj; }
        }
        if (bj != io) {
            out[1 + (size_t)b * CHW + (size_t)lane * HWD + hw] = cb[(size_t)bj * KDIM + lane];
            if (lane == 0) atomicAdd(loss_adj, best - (m1o + znorm));
        }
    }

    __syncthreads();
    if (threadIdx.x == 0) {
        __threadfence();
        last_s = (atomicAdd(done_cnt, 1) == (int)gridDim.x - 1) ? 1 : 0;
    }
    __syncthreads();

    if (last_s) {
        // all other blocks' loss_adj atomics + vq_main partials are visible
        float s = 0.0f;
        for (int i = threadIdx.x; i < 1024; i += 256) s += loss_part[i];
        #pragma unroll
        for (int sh = 1; sh < 64; sh <<= 1) s += __shfl_xor(s, sh, 64);
        if (lane == 0) red_s[w] = s;
        __syncthreads();
        if (threadIdx.x == 0) {
            float L = red_s[0] + red_s[1] + red_s[2] + red_s[3]
                    + atomicAdd(loss_adj, 0.0f);
            out[0] = 1.25f * L / TOTALF;
        }
    }
}

extern "C" void kernel_launch(void* const* d_in, const int* in_sizes, int n_in,
                              void* d_out, int out_size, void* d_ws, size_t ws_size,
                              hipStream_t stream) {
    const float* z  = (const float*)d_in[0];
    const float* cb = (const float*)d_in[1];
    float* out      = (float*)d_out;
    char*  ws       = (char*)d_ws;

    float*          loss_adj  = (float*)(ws + 0);
    int*            flag_cnt  = (int*)(ws + 4);
    int*            done_cnt  = (int*)(ws + 8);
    float*          loss_part = (float*)(ws + 128);
    float*          norms     = (float*)(ws + 4224);
    unsigned short* cbh       = (unsigned short*)(ws + 8320);
    int*            flag_q    = (int*)(ws + 266368);
    float*          flag_m1   = (float*)(ws + 331904);
    int*            flag_idx  = (int*)(ws + 397440);

    vq_prep<<<dim3(16), dim3(256), 0, stream>>>(cb, norms, cbh,
                                                loss_adj, flag_cnt, done_cnt);

    vq_main<<<dim3(NQ / 128), dim3(256), 0, stream>>>(z, cb, cbh, norms, out,
                                                      loss_part, flag_q, flag_m1,
                                                      flag_idx, flag_cnt);

    vq_fix<<<dim3(256), dim3(256), 0, stream>>>(z, cb, out, loss_adj, loss_part,
                                                flag_q, flag_m1, flag_idx,
                                                flag_cnt, done_cnt);
}

// Round 4
// 167.055 us; speedup vs baseline: 1.6665x; 1.1712x over previous
//
#include <hip/hip_runtime.h>

// VQ-VAE VectorQuantizer: fp16 single-term MFMA distance + exact fp32 fallback.
// z: (32,64,64,64) NCHW fp32; codebook: (1024,64) fp32.
// d_out: [0]=loss, [1..]=z_q (NCHW).
//
// R12 (from R11 post-mortem): R11's vq_fix only scanned 256/1024 codes
// (16 passes x 16 codes-per-pass; j = p*64+cg skips j%64>=16) -> overwrote
// correct z_q rows with worse codes (absmax 1.996). Fix: 64 passes,
// j = p*16 + cg. Structure kept: 16 register-resident z dims/lane,
// coalesced cb reads, quad shuffles finish distances, first-min tie-break
// (j ascends per lane; cross-lane reduce takes smaller j on ties),
// __launch_bounds__(256,1) so nothing spills.
// vq_main / vq_prep unchanged (R10-proven: 76-VGPR no-spill, per-block loss
// partials, batched flag atomics, fp16 single-term MFMA, LDS dbuf).

#define CB_N   1024
#define KDIM   64
#define HWD    4096
#define CHW    (KDIM * HWD)
#define NQ     131072
#define TOTALF 8388608.0f
#define TAU    0.02f
#define FCAP   16384
#define CHUNK  128            // codes per LDS chunk
#define NCHUNK (CB_N / CHUNK)

typedef __attribute__((ext_vector_type(8))) _Float16 half8;
typedef __attribute__((ext_vector_type(4))) float    f32x4;

// async 16B/lane global->LDS copy (wave-uniform contiguous; m97 pattern)
__device__ __forceinline__ void gload_lds16(const void* g, void* l) {
    __builtin_amdgcn_global_load_lds(
        (const __attribute__((address_space(1))) unsigned int*)g,
        (__attribute__((address_space(3))) unsigned int*)l,
        16, 0, 0);
}

// ---------- ws layout (byte offsets) ----------
// 0: loss_adj  4: flag_cnt  8: done_cnt
// 128:    loss_part f32[1024]
// 4224:   norms     f32[1024]
// 8320:   cbh_sw    u16[1024*64]   (fp16, rotate-swizzled row segments)
// 266368: flag_q i32[FCAP]  331904: flag_m1 f32[FCAP]  397440: flag_idx i32[FCAP]

// ---------------- prep: fp16 convert, swizzled rows, norms, counters --------
__global__ void vq_prep(const float* __restrict__ cb,
                        float* __restrict__ norms,
                        unsigned short* __restrict__ cbh,
                        float* __restrict__ loss_adj,
                        int* __restrict__ flag_cnt,
                        int* __restrict__ done_cnt) {
    const int tid = blockIdx.x * 256 + threadIdx.x;
    if (tid == 0) *loss_adj = 0.0f;
    if (tid == 1) *flag_cnt = 0;
    if (tid == 2) *done_cnt = 0;
    const int j  = tid >> 2;
    const int s2 = tid & 3;

    const float4* r4 = (const float4*)(cb + (size_t)j * KDIM);
    float s_norm = 0.0f;
    #pragma unroll
    for (int seg8 = 0; seg8 < 2; ++seg8) {
        const int s = s2 * 2 + seg8;
        float4 v0 = r4[s * 2 + 0];
        float4 v1 = r4[s * 2 + 1];
        float e[8] = {v0.x, v0.y, v0.z, v0.w, v1.x, v1.y, v1.z, v1.w};
        unsigned hh[4];
        #pragma unroll
        for (int c = 0; c < 8; ++c) {
            float x = e[c];
            s_norm = fmaf(x, x, s_norm);
            union { _Float16 h; unsigned short u; } cv;
            cv.h = (_Float16)x;                       // RNE fp16
            if ((c & 1) == 0) hh[c >> 1] = cv.u;
            else              hh[c >> 1] |= ((unsigned)cv.u) << 16;
        }
        const int p = (s + j) & 7;                    // bank-deconflict rotate
        *(uint4*)(cbh + (size_t)j * KDIM + p * 8) = make_uint4(hh[0], hh[1], hh[2], hh[3]);
    }
    s_norm += __shfl_xor(s_norm, 1, 64);
    s_norm += __shfl_xor(s_norm, 2, 64);
    if (s2 == 0) norms[j] = s_norm;
}

// ---------------- main ------------------------------------------------------
__global__ __launch_bounds__(256, 3) void vq_main(
        const float* __restrict__ z,
        const float* __restrict__ cb,
        const unsigned short* __restrict__ cbh,
        const float* __restrict__ norms,
        float* __restrict__ out,
        float* __restrict__ loss_part,
        int* __restrict__ flag_q,
        float* __restrict__ flag_m1,
        int* __restrict__ flag_idx,
        int* __restrict__ flag_cnt) {
    __shared__ float          norms_s[CB_N];             // 4 KB
    __shared__ unsigned short bh_s[2][CHUNK * KDIM];     // 2 x 16 KB (dbuf)
    __shared__ float          zn_s[128];
    __shared__ int            idx_s[128];
    __shared__ float          wsum_s[4];

    const int tid  = threadIdx.x;
    const int w    = tid >> 6;
    const int lane = tid & 63;
    const int quad = lane >> 4;
    const int l16  = lane & 15;
    const int qb   = blockIdx.x * 128;     // block's 128 queries (same batch b)
    const int b    = qb >> 12;
    const int hw0  = qb & 4095;
    const int ch0  = blockIdx.x & (NCHUNK - 1);   // de-phase chunk start

    // ---- issue stage of chunk 0 FIRST (flies under the z-read prologue)
    {
        const char* gh = (const char*)cbh + (size_t)(ch0 & (NCHUNK - 1)) * (CHUNK * KDIM * 2);
        char* lh = (char*)(&bh_s[0][0]);
        #pragma unroll
        for (int i = 0; i < 4; ++i) {
            const int off = (w * 4 + i) * 1024 + lane * 16;
            gload_lds16(gh + off, lh + off);
        }
    }

    // ---- stage all code norms into LDS
    *(float4*)(norms_s + tid * 4) = *(const float4*)(norms + tid * 4);

    // ---- stage A-frags: wave w owns queries [32w, 32w+32); 2 tiles of 16.
    const float* zbase = z + (size_t)b * CHW + hw0 + 32 * w;
    half8 ah[2][2];
    float znp[2] = {0.f, 0.f};
    #pragma unroll
    for (int t = 0; t < 2; ++t)
        #pragma unroll
        for (int ks = 0; ks < 2; ++ks)
            #pragma unroll
            for (int j = 0; j < 8; ++j) {
                float v = zbase[(size_t)(ks * 32 + quad * 8 + j) * HWD + t * 16 + l16];
                znp[t] = fmaf(v, v, znp[t]);
                ah[t][ks][j] = (_Float16)(-2.0f * v);   // RNE fp16
            }
    #pragma unroll
    for (int t = 0; t < 2; ++t) {
        znp[t] += __shfl_xor(znp[t], 16, 64);
        znp[t] += __shfl_xor(znp[t], 32, 64);
    }
    if (lane < 16) {
        zn_s[32 * w + lane]      = znp[0];
        zn_s[32 * w + 16 + lane] = znp[1];
    }

    float m1[2][4], m2[2][4];
    int   i1[2][4];
    #pragma unroll
    for (int t = 0; t < 2; ++t)
        #pragma unroll
        for (int r = 0; r < 4; ++r) { m1[t][r] = 3.4e38f; m2[t][r] = 3.4e38f; i1[t][r] = 0; }

    // loop-invariant swizzled segment offsets (ks=0 / ks=1)
    const int p0 = ((quad + l16) & 7) * 8;
    const int p1 = ((4 + quad + l16) & 7) * 8;

    f32x4 bank[2][2];               // [tile-parity][t] -- deferred tracking
    bank[0][0] = bank[0][1] = (f32x4){0.f, 0.f, 0.f, 0.f};
    bank[1][0] = bank[1][1] = (f32x4){0.f, 0.f, 0.f, 0.f};
    int prevCode = 0;

    __syncthreads();                // chunk 0 staged + norms_s/zn_s visible
    int cur = 0;

    for (int cc = 0; cc < NCHUNK; ++cc) {
        // ---- issue next chunk's stage into the OTHER buffer (overlaps compute)
        if (cc + 1 < NCHUNK) {
            const int chn = (cc + 1 + ch0) & (NCHUNK - 1);
            const char* gh = (const char*)cbh + (size_t)chn * (CHUNK * KDIM * 2);
            char* lh = (char*)(&bh_s[cur ^ 1][0]);
            #pragma unroll
            for (int i = 0; i < 4; ++i) {
                const int off = (w * 4 + i) * 1024 + lane * 16;
                gload_lds16(gh + off, lh + off);
            }
        }

        const int ch = (cc + ch0) & (NCHUNK - 1);
        #pragma unroll
        for (int t8 = 0; t8 < 8; ++t8) {
            const int crow = t8 * 16 + l16;            // chunk-local code row
            const float nv = norms_s[ch * CHUNK + crow];
            const half8 bh0 = *(const half8*)(&bh_s[cur][crow * KDIM + p0]);
            const half8 bh1 = *(const half8*)(&bh_s[cur][crow * KDIM + p1]);
            const int code = ch * CHUNK + crow;
            const int bk = t8 & 1, pv = bk ^ 1;

            // track the DEFERRED tile (previous t8) held in bank[pv];
            // independent of bank[bk]'s MFMAs below -> overlaps them
            if (cc + t8 > 0) {
                #pragma unroll
                for (int t = 0; t < 2; ++t)
                    #pragma unroll
                    for (int r = 0; r < 4; ++r) {
                        float d = bank[pv][t][r];
                        bool cnd = d < m1[t][r];
                        m2[t][r] = __builtin_amdgcn_fmed3f(d, m1[t][r], m2[t][r]);
                        m1[t][r] = fminf(m1[t][r], d);
                        i1[t][r] = cnd ? prevCode : i1[t][r];
                    }
            }

            #pragma unroll
            for (int t = 0; t < 2; ++t) {
                f32x4 acc = {nv, nv, nv, nv};
                acc = __builtin_amdgcn_mfma_f32_16x16x32_f16(ah[t][0], bh0, acc, 0, 0, 0);
                acc = __builtin_amdgcn_mfma_f32_16x16x32_f16(ah[t][1], bh1, acc, 0, 0, 0);
                bank[bk][t] = acc;
            }
            prevCode = code;
        }

        __syncthreads();   // implicit vmcnt(0): next buffer landed; cur reads done
        cur ^= 1;
    }
    // final deferred tile (last t8=7 wrote bank[1])
    {
        #pragma unroll
        for (int t = 0; t < 2; ++t)
            #pragma unroll
            for (int r = 0; r < 4; ++r) {
                float d = bank[1][t][r];
                bool cnd = d < m1[t][r];
                m2[t][r] = __builtin_amdgcn_fmed3f(d, m1[t][r], m2[t][r]);
                m1[t][r] = fminf(m1[t][r], d);
                i1[t][r] = cnd ? prevCode : i1[t][r];
            }
    }

    // ---- merge across 16 lanes (code residues), first-index ties
    #pragma unroll
    for (int s = 1; s < 16; s <<= 1)
        #pragma unroll
        for (int t = 0; t < 2; ++t)
            #pragma unroll
            for (int r = 0; r < 4; ++r) {
                float o1 = __shfl_xor(m1[t][r], s, 64);
                int   oi = __shfl_xor(i1[t][r], s, 64);
                float o2 = __shfl_xor(m2[t][r], s, 64);
                m2[t][r] = __builtin_amdgcn_fmed3f(m1[t][r], o1, fminf(m2[t][r], o2));
                if (o1 < m1[t][r] || (o1 == m1[t][r] && oi < i1[t][r])) {
                    m1[t][r] = o1; i1[t][r] = oi;
                }
            }

    // ---- owners (l16==0): publish idx, batched flags, loss partial
    float lsum = 0.0f;
    if (l16 == 0) {
        int nf = 0;
        #pragma unroll
        for (int t = 0; t < 2; ++t)
            #pragma unroll
            for (int r = 0; r < 4; ++r) {
                const int ql = 32 * w + t * 16 + quad * 4 + r;
                idx_s[ql] = i1[t][r];
                lsum += m1[t][r] + zn_s[ql];
                nf += (m2[t][r] - m1[t][r] < TAU) ? 1 : 0;
            }
        if (nf) {                      // ONE atomic per flagging owner thread
            int pos = atomicAdd(flag_cnt, nf);
            #pragma unroll
            for (int t = 0; t < 2; ++t)
                #pragma unroll
                for (int r = 0; r < 4; ++r)
                    if (m2[t][r] - m1[t][r] < TAU) {
                        if (pos < FCAP) {
                            flag_q[pos]   = qb + 32 * w + t * 16 + quad * 4 + r;
                            flag_m1[pos]  = m1[t][r];
                            flag_idx[pos] = i1[t][r];
                        }
                        ++pos;
                    }
        }
    }
    #pragma unroll
    for (int s = 1; s < 64; s <<= 1) lsum += __shfl_xor(lsum, s, 64);
    if (lane == 0) wsum_s[w] = lsum;
    __syncthreads();                   // idx_s + wsum_s visible

    // per-block loss partial: plain store, NO global atomic
    if (tid == 0)
        loss_part[blockIdx.x] = wsum_s[0] + wsum_s[1] + wsum_s[2] + wsum_s[3];

    // ---- epilogue: thread -> (query tid&127, channels [32*(tid>>7),+32))
    {
        const int q   = tid & 127;
        const int cs  = (tid >> 7) * 32;
        const int idx = idx_s[q];
        const float4* row = (const float4*)(cb + (size_t)idx * KDIM + cs);
        float* op = out + 1 + (size_t)b * CHW + (size_t)cs * HWD + hw0 + q;
        #pragma unroll
        for (int i4 = 0; i4 < 8; ++i4) {
            float4 v = row[i4];
            op[(size_t)(i4 * 4 + 0) * HWD] = v.x;
            op[(size_t)(i4 * 4 + 1) * HWD] = v.y;
            op[(size_t)(i4 * 4 + 2) * HWD] = v.z;
            op[(size_t)(i4 * 4 + 3) * HWD] = v.w;
        }
    }
}

// ---------------- fix: exact fp32 re-rank for flagged queries + finalize ----
// lane = (code-in-pass lane>>2, dim-segment lane&3). Each lane holds 16 z dims
// in registers; cb loads are coalesced 16B chunks; two intra-quad shuffles
// finish each distance; 64 passes x 16 codes = all 1024 codes (R11 bug: 16
// passes with j=p*64+cg covered only 256).
__global__ __launch_bounds__(256, 1) void vq_fix(
                       const float* __restrict__ z,
                       const float* __restrict__ cb,
                       float* __restrict__ out,
                       float* __restrict__ loss_adj,
                       const float* __restrict__ loss_part,
                       const int* __restrict__ flag_q,
                       const float* __restrict__ flag_m1,
                       const int* __restrict__ flag_idx,
                       const int* __restrict__ flag_cnt,
                       int* __restrict__ done_cnt) {
    __shared__ float red_s[4];
    __shared__ int   last_s;

    const int w    = threadIdx.x >> 6;
    const int lane = threadIdx.x & 63;
    const int seg  = lane & 3;          // 16-dim segment of the query
    const int cg   = lane >> 2;         // code-in-pass 0..15
    const int gw   = blockIdx.x * 4 + w;
    const int NW   = gridDim.x * 4;

    int n = *flag_cnt;
    if (n > FCAP) n = FCAP;

    for (int f = gw; f < n; f += NW) {
        const int   q   = flag_q[f];
        const float m1o = flag_m1[f];
        const int   io  = flag_idx[f];
        const int   b   = q >> 12;
        const int   hw  = q & 4095;

        // 16 register-resident z dims per lane (segment seg)
        float zq[16];
        float zpart = 0.0f;
        #pragma unroll
        for (int i = 0; i < 16; ++i) {
            zq[i] = z[(size_t)b * CHW + (size_t)(seg * 16 + i) * HWD + hw];
            zpart = fmaf(zq[i], zq[i], zpart);
        }
        float znorm = zpart;
        znorm += __shfl_xor(znorm, 1, 64);
        znorm += __shfl_xor(znorm, 2, 64);   // full ||z||^2 in every lane

        float best = 3.4e38f; int bj = 0;
        #pragma unroll 4
        for (int p = 0; p < 64; ++p) {
            const int j = p * 16 + cg;       // 64 passes x 16 codes = 1024
            const float4* rp = (const float4*)(cb + (size_t)j * KDIM + seg * 16);
            float d = 0.0f;
            #pragma unroll
            for (int q4 = 0; q4 < 4; ++q4) {
                float4 v = rp[q4];
                float t0 = zq[q4 * 4 + 0] - v.x;
                float t1 = zq[q4 * 4 + 1] - v.y;
                float t2 = zq[q4 * 4 + 2] - v.z;
                float t3 = zq[q4 * 4 + 3] - v.w;
                d = fmaf(t0, t0, d); d = fmaf(t1, t1, d);
                d = fmaf(t2, t2, d); d = fmaf(t3, t3, d);
            }
            d += __shfl_xor(d, 1, 64);
            d += __shfl_xor(d, 2, 64);       // full distance of code j (quad)
            if (d < best) { best = d; bj = j; }  // j ascends per lane: first-min
        }
        // reduce across 16 code-groups (quad lanes identical): steps 4..32
        #pragma unroll
        for (int s = 4; s < 64; s <<= 1) {
            float ob = __shfl_xor(best, s, 64);
            int   oj = __shfl_xor(bj, s, 64);
            if (ob < best || (ob == best && oj < bj)) { best = ob; bj = oj; }
        }
        if (bj != io) {
            out[1 + (size_t)b * CHW + (size_t)lane * HWD + hw] = cb[(size_t)bj * KDIM + lane];
            if (lane == 0) atomicAdd(loss_adj, best - (m1o + znorm));
        }
    }

    __syncthreads();
    if (threadIdx.x == 0) {
        __threadfence();
        last_s = (atomicAdd(done_cnt, 1) == (int)gridDim.x - 1) ? 1 : 0;
    }
    __syncthreads();

    if (last_s) {
        // all other blocks' loss_adj atomics + vq_main partials are visible
        float s = 0.0f;
        for (int i = threadIdx.x; i < 1024; i += 256) s += loss_part[i];
        #pragma unroll
        for (int sh = 1; sh < 64; sh <<= 1) s += __shfl_xor(s, sh, 64);
        if (lane == 0) red_s[w] = s;
        __syncthreads();
        if (threadIdx.x == 0) {
            float L = red_s[0] + red_s[1] + red_s[2] + red_s[3]
                    + atomicAdd(loss_adj, 0.0f);
            out[0] = 1.25f * L / TOTALF;
        }
    }
}

extern "C" void kernel_launch(void* const* d_in, const int* in_sizes, int n_in,
                              void* d_out, int out_size, void* d_ws, size_t ws_size,
                              hipStream_t stream) {
    const float* z  = (const float*)d_in[0];
    const float* cb = (const float*)d_in[1];
    float* out      = (float*)d_out;
    char*  ws       = (char*)d_ws;

    float*          loss_adj  = (float*)(ws + 0);
    int*            flag_cnt  = (int*)(ws + 4);
    int*            done_cnt  = (int*)(ws + 8);
    float*          loss_part = (float*)(ws + 128);
    float*          norms     = (float*)(ws + 4224);
    unsigned short* cbh       = (unsigned short*)(ws + 8320);
    int*            flag_q    = (int*)(ws + 266368);
    float*          flag_m1   = (float*)(ws + 331904);
    int*            flag_idx  = (int*)(ws + 397440);

    vq_prep<<<dim3(16), dim3(256), 0, stream>>>(cb, norms, cbh,
                                                loss_adj, flag_cnt, done_cnt);

    vq_main<<<dim3(NQ / 128), dim3(256), 0, stream>>>(z, cb, cbh, norms, out,
                                                      loss_part, flag_q, flag_m1,
                                                      flag_idx, flag_cnt);

    vq_fix<<<dim3(256), dim3(256), 0, stream>>>(z, cb, out, loss_adj, loss_part,
                                                flag_q, flag_m1, flag_idx,
                                                flag_cnt, done_cnt);
}